// Round 6
// baseline (368.136 us; speedup 1.0000x reference)
//
#include <hip/hip_runtime.h>
#include <hip/hip_bf16.h>

// Problem: B=4, L=4096, DH=1024, T=1024, DG=768, P=256
// Inputs fp32 (H,G,Wk,Wq) + bool mask (width auto-detect). OUTPUT: FP32
// (reference output dtype is float32 -> d_out is float*). Compute in bf16
// MFMA with fp32 accumulate (allowed by harness bf16 tolerance).
// Pipeline:
//   0) convert Wk,Wq,H,G fp32 -> bf16 in ws
//   1) Qbf = Gbf @ Wqbf^T        [B*T, P]    (bf16)
//   2) Kbf = Hbf @ Wkbf^T        [B*L, P]    (bf16)
//   3) S   = Qbf @ Kbf^T / 16    [B, T, L]   (fp32)
//   4) Ht  = transpose(H) fp32->bf16  [B, DH, L]  (overwrites dead Hbf)
//   5) mask width detect
//   6) masked softmax rows of S -> alpha bf16 in place (row stride 2*L)
//   7) Z   = alpha @ Ht^T        [B, T, DH]  (FP32 out)

typedef __attribute__((ext_vector_type(8))) short short8;   // 8 bf16 = 4 VGPRs
typedef __attribute__((ext_vector_type(4))) float f32x4;

static __device__ __forceinline__ unsigned short bf16bits(float x) {
    __hip_bfloat16 b = __float2bfloat16(x);
    return *(unsigned short*)&b;
}

// ---------------------------------------------------------------------------
// Elementwise fp32 -> bf16, 4 per thread. n4 = n/4.
// ---------------------------------------------------------------------------
__global__ __launch_bounds__(256)
void cvt_f32_bf16_kernel(const float* __restrict__ in,
                         unsigned short* __restrict__ out, int n4)
{
    const int i = blockIdx.x * 256 + threadIdx.x;
    if (i >= n4) return;
    float4 v = ((const float4*)in)[i];
    ushort4 o;
    o.x = bf16bits(v.x); o.y = bf16bits(v.y);
    o.z = bf16bits(v.z); o.w = bf16bits(v.w);
    ((ushort4*)out)[i] = o;
}

// ---------------------------------------------------------------------------
// GEMM: C[M,N] = scale * A[M,K] @ Bm[N,K]^T   (bf16 row-major, K contiguous)
// 128x128 block tile, 4 waves, each wave 64x64 via 4x4 MFMA 16x16x32 bf16.
// ---------------------------------------------------------------------------
template <typename OutT>
__global__ __launch_bounds__(256)
void gemm_bt_kernel(const __hip_bfloat16* __restrict__ A,
                    const __hip_bfloat16* __restrict__ Bm,
                    OutT* __restrict__ C,
                    int K, int lda, int ldb, int ldc,
                    long batchStrideA, long batchStrideB, long batchStrideC,
                    float scale)
{
    const int b = blockIdx.z;
    A  += (long)b * batchStrideA;
    Bm += (long)b * batchStrideB;
    C  += (long)b * batchStrideC;

    const int tid  = threadIdx.x;
    const int lane = tid & 63;
    const int wave = tid >> 6;
    const int wm = (wave & 1) * 64;
    const int wn = (wave >> 1) * 64;
    const int rowBase = blockIdx.x * 128;
    const int colBase = blockIdx.y * 128;

    __shared__ __hip_bfloat16 As[128][40];   // +8 pad: b128 align kept, bank walk broken
    __shared__ __hip_bfloat16 Bs[128][40];

    f32x4 acc[4][4];
    #pragma unroll
    for (int i = 0; i < 4; ++i)
        #pragma unroll
        for (int j = 0; j < 4; ++j)
            acc[i][j] = (f32x4){0.f, 0.f, 0.f, 0.f};

    const int sr = tid >> 2;        // 0..63: staging row
    const int sc = (tid & 3) * 8;   // 0,8,16,24: staging col (8 bf16 = 16B)
    const int mrow = lane & 15;     // fragment m/n index
    const int koff = (lane >> 4) * 8;

    for (int k0 = 0; k0 < K; k0 += 32) {
        uint4 av0 = *(const uint4*)(A  + (long)(rowBase + sr)      * lda + k0 + sc);
        uint4 av1 = *(const uint4*)(A  + (long)(rowBase + sr + 64) * lda + k0 + sc);
        uint4 bv0 = *(const uint4*)(Bm + (long)(colBase + sr)      * ldb + k0 + sc);
        uint4 bv1 = *(const uint4*)(Bm + (long)(colBase + sr + 64) * ldb + k0 + sc);
        __syncthreads();
        *(uint4*)(&As[sr][sc])      = av0;
        *(uint4*)(&As[sr + 64][sc]) = av1;
        *(uint4*)(&Bs[sr][sc])      = bv0;
        *(uint4*)(&Bs[sr + 64][sc]) = bv1;
        __syncthreads();

        short8 af[4], bf[4];
        #pragma unroll
        for (int mi = 0; mi < 4; ++mi)
            af[mi] = *(const short8*)(&As[wm + mi * 16 + mrow][koff]);
        #pragma unroll
        for (int ni = 0; ni < 4; ++ni)
            bf[ni] = *(const short8*)(&Bs[wn + ni * 16 + mrow][koff]);

        #pragma unroll
        for (int mi = 0; mi < 4; ++mi)
            #pragma unroll
            for (int ni = 0; ni < 4; ++ni)
                acc[mi][ni] = __builtin_amdgcn_mfma_f32_16x16x32_bf16(
                    af[mi], bf[ni], acc[mi][ni], 0, 0, 0);
    }

    // C/D layout (verified m89/m91): col = lane&15, row = (lane>>4)*4 + r
    const int crow0 = (lane >> 4) * 4;
    const int ccol  = lane & 15;
    #pragma unroll
    for (int mi = 0; mi < 4; ++mi) {
        #pragma unroll
        for (int ni = 0; ni < 4; ++ni) {
            #pragma unroll
            for (int r = 0; r < 4; ++r) {
                const int row = rowBase + wm + mi * 16 + crow0 + r;
                const int col = colBase + wn + ni * 16 + ccol;
                const float v = acc[mi][ni][r] * scale;
                if constexpr (sizeof(OutT) == 2) {
                    C[(long)row * ldc + col] = __float2bfloat16(v);
                } else {
                    C[(long)row * ldc + col] = v;
                }
            }
        }
    }
}

// ---------------------------------------------------------------------------
// Transpose + convert per batch: Ht[b][d][l] = bf16(H[b][l][d]), H fp32.
// ---------------------------------------------------------------------------
__global__ __launch_bounds__(256)
void transpose_cvt_kernel(const float* __restrict__ H,
                          __hip_bfloat16* __restrict__ Ht, int L, int D)
{
    const long b = blockIdx.z;
    const float* Hb = H + b * (long)L * D;
    __hip_bfloat16* Htb = Ht + b * (long)D * L;
    __shared__ float tile[32][33];
    const int l0 = blockIdx.x * 32, d0 = blockIdx.y * 32;
    const int tx = threadIdx.x & 31, ty = threadIdx.x >> 5;  // 32 x 8
    #pragma unroll
    for (int j = 0; j < 4; ++j)
        tile[ty + j * 8][tx] = Hb[(long)(l0 + ty + j * 8) * D + d0 + tx];
    __syncthreads();
    #pragma unroll
    for (int j = 0; j < 4; ++j)
        Htb[(long)(d0 + ty + j * 8) * L + l0 + tx] = __float2bfloat16(tile[tx][ty + j * 8]);
}

// ---------------------------------------------------------------------------
// Mask element-width detector (mask: 16384 bools, ~50% True). Count nonzero
// fractions at widths 1/2/4/8 B in the first 16384 bytes; true width ~0.5.
// Byte-vs-u16 tie broken by byte-pair equality.
// ---------------------------------------------------------------------------
__global__ __launch_bounds__(256)
void mask_width_kernel(const unsigned char* __restrict__ m, int* __restrict__ widthOut)
{
    __shared__ int c1, c2, c4, c8, cp;
    if (threadIdx.x == 0) { c1 = c2 = c4 = c8 = cp = 0; }
    __syncthreads();
    int l1 = 0, l2 = 0, l4 = 0, l8 = 0, lp = 0;
    const unsigned short* m16 = (const unsigned short*)m;
    const unsigned int*   m32 = (const unsigned int*)m;
    for (int i = threadIdx.x; i < 16384; i += 256) l1 += (m[i] != 0);
    for (int i = threadIdx.x; i < 8192;  i += 256) {
        l2 += (m16[i] != 0);
        lp += ((m[2 * i] != 0) == (m[2 * i + 1] != 0));
    }
    for (int i = threadIdx.x; i < 4096;  i += 256) l4 += (m32[i] != 0);
    for (int i = threadIdx.x; i < 2048;  i += 256) l8 += ((m32[2 * i] | m32[2 * i + 1]) != 0);
    atomicAdd(&c1, l1); atomicAdd(&c2, l2); atomicAdd(&c4, l4);
    atomicAdd(&c8, l8); atomicAdd(&cp, lp);
    __syncthreads();
    if (threadIdx.x == 0) {
        const float f1 = fabsf(c1 / 16384.f - 0.5f);
        const float f2 = fabsf(c2 / 8192.f  - 0.5f);
        const float f4 = fabsf(c4 / 4096.f  - 0.5f);
        const float f8 = fabsf(c8 / 2048.f  - 0.5f);
        int w = 1; float best = f1;
        if (f2 < best) { best = f2; w = 2; }
        if (f4 < best) { best = f4; w = 4; }
        if (f8 < best) { best = f8; w = 8; }
        if (w == 1 && cp > 7400) w = 2;
        *widthOut = w;
    }
}

// ---------------------------------------------------------------------------
// Row softmax with key mask. One block per (b,t) row. Writes bf16 alpha
// IN PLACE over the fp32 row's first half (alpha row stride = 2*L bf16).
// ---------------------------------------------------------------------------
__global__ __launch_bounds__(256)
void softmax_kernel(float* __restrict__ S, const void* __restrict__ mask,
                    const int* __restrict__ widthPtr, int L, int T)
{
    const int row  = blockIdx.x;          // b*T + t
    const int bidx = row / T;
    const float* Srow = S + (long)row * L;
    __hip_bfloat16* arow = (__hip_bfloat16*)S + (long)row * 2 * L;

    const int w = *widthPtr;
    const unsigned char*  m8  = (const unsigned char*)mask;
    const unsigned short* m16 = (const unsigned short*)mask;
    const unsigned int*   m32 = (const unsigned int*)mask;
    const uint2*          m64 = (const uint2*)mask;

    const int tid = threadIdx.x;
    float v[16];
    float mx = -INFINITY;
    #pragma unroll
    for (int i = 0; i < 16; ++i) {
        const int l = tid + i * 256;
        const long idx = (long)bidx * L + l;
        bool masked;
        if (w == 4)      masked = (m32[idx] != 0);
        else if (w == 1) masked = (m8[idx] != 0);
        else if (w == 2) masked = (m16[idx] != 0);
        else             { uint2 q = m64[idx]; masked = ((q.x | q.y) != 0); }
        float x = Srow[l];
        if (masked) x = -INFINITY;
        v[i] = x;
        mx = fmaxf(mx, x);
    }
    #pragma unroll
    for (int off = 1; off < 64; off <<= 1)
        mx = fmaxf(mx, __shfl_xor(mx, off, 64));
    __shared__ float redmx[4];
    if ((tid & 63) == 0) redmx[tid >> 6] = mx;
    __syncthreads();   // also: all Srow reads complete before in-place write
    mx = fmaxf(fmaxf(redmx[0], redmx[1]), fmaxf(redmx[2], redmx[3]));

    float s = 0.f;
    #pragma unroll
    for (int i = 0; i < 16; ++i) {
        const float e = (v[i] == -INFINITY) ? 0.f : __expf(v[i] - mx);
        v[i] = e;
        s += e;
    }
    #pragma unroll
    for (int off = 1; off < 64; off <<= 1)
        s += __shfl_xor(s, off, 64);
    __shared__ float redsm[4];
    if ((tid & 63) == 0) redsm[tid >> 6] = s;
    __syncthreads();
    s = redsm[0] + redsm[1] + redsm[2] + redsm[3];
    const float inv = (s > 0.f) ? (1.f / s) : 0.f;

    #pragma unroll
    for (int i = 0; i < 16; ++i) {
        const int l = tid + i * 256;
        arow[l] = __float2bfloat16(v[i] * inv);
    }
}

// ---------------------------------------------------------------------------
extern "C" void kernel_launch(void* const* d_in, const int* in_sizes, int n_in,
                              void* d_out, int out_size, void* d_ws, size_t ws_size,
                              hipStream_t stream)
{
    constexpr int B = 4, L = 4096, DH = 1024, T = 1024, DG = 768, P = 256;

    const float* H  = (const float*)d_in[0];
    const float* G  = (const float*)d_in[1];
    const void*  mask = d_in[2];
    const float* Wk = (const float*)d_in[3];
    const float* Wq = (const float*)d_in[4];
    for (int i = 0; i < n_in; ++i) {
        switch (in_sizes[i]) {
            case B * L * DH: H    = (const float*)d_in[i]; break;   // 16777216
            case B * T * DG: G    = (const float*)d_in[i]; break;   // 3145728
            case B * L:      mask = d_in[i];               break;   // 16384
            case P * DH:     Wk   = (const float*)d_in[i]; break;   // 262144
            case P * DG:     Wq   = (const float*)d_in[i]; break;   // 196608
        }
    }
    float* Z = (float*)d_out;   // reference output dtype is float32

    char* ws = (char*)d_ws;
    __hip_bfloat16* Hbf  = (__hip_bfloat16*)ws;                      // [0, 32 MiB)
    __hip_bfloat16* Gbf  = (__hip_bfloat16*)(ws + (32l << 20));      // [32, 38)
    __hip_bfloat16* Qbf  = (__hip_bfloat16*)(ws + (38l << 20));      // [38, 40)
    __hip_bfloat16* Kbf  = (__hip_bfloat16*)(ws + (40l << 20));      // [40, 48)
    __hip_bfloat16* Wkbf = (__hip_bfloat16*)(ws + (48l << 20));      // 512 KiB
    __hip_bfloat16* Wqbf = (__hip_bfloat16*)(ws + (48l << 20) + (512l << 10)); // 384 KiB
    float*          S    = (float*)(ws + (49l << 20));               // [49, 113)
    __hip_bfloat16* Ht   = (__hip_bfloat16*)ws;                      // reuses dead Hbf
    int*            widthFlag = (int*)(ws + (38l << 20));            // reuses dead Qbf

    const dim3 blk(256);

    // 0) fp32 -> bf16 conversions
    cvt_f32_bf16_kernel<<<dim3((P * DH) / 1024), blk, 0, stream>>>(Wk, (unsigned short*)Wkbf, (P * DH) / 4);
    cvt_f32_bf16_kernel<<<dim3((P * DG) / 1024), blk, 0, stream>>>(Wq, (unsigned short*)Wqbf, (P * DG) / 4);
    cvt_f32_bf16_kernel<<<dim3((B * L * DH) / 1024), blk, 0, stream>>>(H, (unsigned short*)Hbf, (B * L * DH) / 4);
    cvt_f32_bf16_kernel<<<dim3((B * T * DG) / 1024), blk, 0, stream>>>(G, (unsigned short*)Gbf, (B * T * DG) / 4);

    // 1) Q = G @ Wq^T   [B*T, P]
    gemm_bt_kernel<__hip_bfloat16><<<dim3((B * T) / 128, P / 128, 1), blk, 0, stream>>>(
        Gbf, Wqbf, Qbf, DG, DG, DG, P, 0, 0, 0, 1.0f);
    // 2) K = H @ Wk^T   [B*L, P]
    gemm_bt_kernel<__hip_bfloat16><<<dim3((B * L) / 128, P / 128, 1), blk, 0, stream>>>(
        Hbf, Wkbf, Kbf, DH, DH, DH, P, 0, 0, 0, 1.0f);
    // 3) S = Q @ K^T * P^-0.5   per batch, fp32 out
    gemm_bt_kernel<float><<<dim3(T / 128, L / 128, B), blk, 0, stream>>>(
        Qbf, Kbf, S, P, P, P, L,
        (long)T * P, (long)L * P, (long)T * L, 0.0625f);
    // 4) Ht = H^T (fp32 -> bf16), overwrites dead Hbf
    transpose_cvt_kernel<<<dim3(L / 32, DH / 32, B), blk, 0, stream>>>(H, Ht, L, DH);
    // 5) mask element-width detection (Qbf region dead now)
    mask_width_kernel<<<dim3(1), blk, 0, stream>>>((const unsigned char*)mask, widthFlag);
    // 6) masked softmax rows -> alpha bf16 in place (row stride 2L)
    softmax_kernel<<<dim3(B * T), blk, 0, stream>>>(S, mask, widthFlag, L, T);
    // 7) Z = alpha @ Ht^T   per batch, FP32 out
    gemm_bt_kernel<float><<<dim3(T / 128, DH / 128, B), blk, 0, stream>>>(
        (const __hip_bfloat16*)S, Ht, Z, L,
        2 * L, L, DH,
        (long)T * 2 * L, (long)DH * L, (long)T * DH, 1.0f);
}

// Round 7
// 358.364 us; speedup vs baseline: 1.0273x; 1.0273x over previous
//
#include <hip/hip_runtime.h>
#include <hip/hip_bf16.h>

// Problem: B=4, L=4096, DH=1024, T=1024, DG=768, P=256
// Inputs fp32 + bool mask (width auto-detect); OUTPUT fp32.
// Pipeline:
//   memset Z
//   0) h_prep: H fp32 -> Hbf [B*L,DH] + Ht [B,DH,L] (one read of H)
//      cvt G, Wk, Wq fp32 -> bf16
//   1) Qbf = Gbf @ Wqbf^T        [B*T, P]   bf16
//   2) Kbf = Hbf @ Wkbf^T        [B*L, P]   bf16
//   3) Sb  = Qbf @ Kbf^T / 16    [B, T, L]  bf16
//   4) mask width probe (flag in dead Qbf region)
//   5) masked softmax rows of Sb -> alpha bf16 in place (stride L)
//   6) Z  += alpha @ Ht^T  split-K x4, fp32 atomicAdd  [B, T, DH]
// Workspace: Hbf[0,32) Ht[32,64) Gbf[64,70) Qbf[70,72) Kbf[72,80)
//            Wkbf[80,80.5) Wqbf[80.5,81) Sb[81,113) MiB; flag @ 70 MiB.

typedef __attribute__((ext_vector_type(8))) short short8;   // 8 bf16 = 4 VGPRs
typedef __attribute__((ext_vector_type(4))) float f32x4;

static __device__ __forceinline__ unsigned short bf16bits(float x) {
    __hip_bfloat16 b = __float2bfloat16(x);
    return *(unsigned short*)&b;
}

// ---------------------------------------------------------------------------
// Elementwise fp32 -> bf16, 4 per thread. n4 = n/4.
// ---------------------------------------------------------------------------
__global__ __launch_bounds__(256)
void cvt_f32_bf16_kernel(const float* __restrict__ in,
                         unsigned short* __restrict__ out, int n4)
{
    const int i = blockIdx.x * 256 + threadIdx.x;
    if (i >= n4) return;
    float4 v = ((const float4*)in)[i];
    ushort4 o;
    o.x = bf16bits(v.x); o.y = bf16bits(v.y);
    o.z = bf16bits(v.z); o.w = bf16bits(v.w);
    ((ushort4*)out)[i] = o;
}

// ---------------------------------------------------------------------------
// H prep: one pass reads H fp32, writes Hbf (row-major bf16 copy) and
// Ht (per-batch transpose, bf16). 32x32 tiles.
// ---------------------------------------------------------------------------
__global__ __launch_bounds__(256)
void h_prep_kernel(const float* __restrict__ H,
                   __hip_bfloat16* __restrict__ Hbf,
                   __hip_bfloat16* __restrict__ Ht, int L, int D)
{
    const long b = blockIdx.z;
    const float* Hb = H + b * (long)L * D;
    __hip_bfloat16* Hbfb = Hbf + b * (long)L * D;
    __hip_bfloat16* Htb  = Ht  + b * (long)D * L;
    __shared__ float tile[32][33];
    const int l0 = blockIdx.x * 32, d0 = blockIdx.y * 32;
    const int tx = threadIdx.x & 31, ty = threadIdx.x >> 5;  // 32 x 8
    #pragma unroll
    for (int j = 0; j < 4; ++j) {
        const float v = Hb[(long)(l0 + ty + j * 8) * D + d0 + tx];
        tile[ty + j * 8][tx] = v;
        Hbfb[(long)(l0 + ty + j * 8) * D + d0 + tx] = __float2bfloat16(v);
    }
    __syncthreads();
    #pragma unroll
    for (int j = 0; j < 4; ++j)
        Htb[(long)(d0 + ty + j * 8) * L + l0 + tx] = __float2bfloat16(tile[tx][ty + j * 8]);
}

// ---------------------------------------------------------------------------
// GEMM: C[M,N] (+)= scale * A[M,K] @ Bm[N,K]^T  (bf16 row-major, K contig)
// 128x128 tile, 4 waves, wave 64x64 via 4x4 MFMA 16x16x32 bf16.
// SPLITK: blockIdx.z = batch*SPLITK + kchunk; each chunk does K/SPLITK.
// ATOMIC: fp32 atomicAdd epilogue (requires OutT=float, zeroed C).
// ---------------------------------------------------------------------------
template <typename OutT, int SPLITK, bool ATOMIC>
__global__ __launch_bounds__(256)
void gemm_bt_kernel(const __hip_bfloat16* __restrict__ A,
                    const __hip_bfloat16* __restrict__ Bm,
                    OutT* __restrict__ C,
                    int K, int lda, int ldb, int ldc,
                    long batchStrideA, long batchStrideB, long batchStrideC,
                    float scale)
{
    const int zb = blockIdx.z / SPLITK;
    const int kc = blockIdx.z % SPLITK;
    A  += (long)zb * batchStrideA;
    Bm += (long)zb * batchStrideB;
    C  += (long)zb * batchStrideC;
    const int Kloc  = K / SPLITK;
    const int kbase = kc * Kloc;

    const int tid  = threadIdx.x;
    const int lane = tid & 63;
    const int wave = tid >> 6;
    const int wm = (wave & 1) * 64;
    const int wn = (wave >> 1) * 64;
    const int rowBase = blockIdx.x * 128;
    const int colBase = blockIdx.y * 128;

    __shared__ __hip_bfloat16 As[128][40];   // +8 pad: b128-aligned, balanced banks
    __shared__ __hip_bfloat16 Bs[128][40];

    f32x4 acc[4][4];
    #pragma unroll
    for (int i = 0; i < 4; ++i)
        #pragma unroll
        for (int j = 0; j < 4; ++j)
            acc[i][j] = (f32x4){0.f, 0.f, 0.f, 0.f};

    const int sr = tid >> 2;        // 0..63: staging row
    const int sc = (tid & 3) * 8;   // 0,8,16,24: staging col (8 bf16 = 16B)
    const int mrow = lane & 15;     // fragment m/n index
    const int koff = (lane >> 4) * 8;

    for (int k0 = 0; k0 < Kloc; k0 += 32) {
        const int kk = kbase + k0 + sc;
        uint4 av0 = *(const uint4*)(A  + (long)(rowBase + sr)      * lda + kk);
        uint4 av1 = *(const uint4*)(A  + (long)(rowBase + sr + 64) * lda + kk);
        uint4 bv0 = *(const uint4*)(Bm + (long)(colBase + sr)      * ldb + kk);
        uint4 bv1 = *(const uint4*)(Bm + (long)(colBase + sr + 64) * ldb + kk);
        __syncthreads();
        *(uint4*)(&As[sr][sc])      = av0;
        *(uint4*)(&As[sr + 64][sc]) = av1;
        *(uint4*)(&Bs[sr][sc])      = bv0;
        *(uint4*)(&Bs[sr + 64][sc]) = bv1;
        __syncthreads();

        short8 af[4], bf[4];
        #pragma unroll
        for (int mi = 0; mi < 4; ++mi)
            af[mi] = *(const short8*)(&As[wm + mi * 16 + mrow][koff]);
        #pragma unroll
        for (int ni = 0; ni < 4; ++ni)
            bf[ni] = *(const short8*)(&Bs[wn + ni * 16 + mrow][koff]);

        #pragma unroll
        for (int mi = 0; mi < 4; ++mi)
            #pragma unroll
            for (int ni = 0; ni < 4; ++ni)
                acc[mi][ni] = __builtin_amdgcn_mfma_f32_16x16x32_bf16(
                    af[mi], bf[ni], acc[mi][ni], 0, 0, 0);
    }

    // C/D layout (verified m89/m91): col = lane&15, row = (lane>>4)*4 + r
    const int crow0 = (lane >> 4) * 4;
    const int ccol  = lane & 15;
    #pragma unroll
    for (int mi = 0; mi < 4; ++mi) {
        #pragma unroll
        for (int ni = 0; ni < 4; ++ni) {
            #pragma unroll
            for (int r = 0; r < 4; ++r) {
                const int row = rowBase + wm + mi * 16 + crow0 + r;
                const int col = colBase + wn + ni * 16 + ccol;
                const float v = acc[mi][ni][r] * scale;
                if constexpr (ATOMIC) {
                    atomicAdd(&C[(long)row * ldc + col], v);
                } else if constexpr (sizeof(OutT) == 2) {
                    C[(long)row * ldc + col] = __float2bfloat16(v);
                } else {
                    C[(long)row * ldc + col] = v;
                }
            }
        }
    }
}

// ---------------------------------------------------------------------------
// Mask element-width detector (16384 bools, ~50% True). Nonzero fractions at
// widths 1/2/4/8 B in the first 16384 bytes; true width ~0.5. Byte-vs-u16
// tie broken by byte-pair equality.
// ---------------------------------------------------------------------------
__global__ __launch_bounds__(256)
void mask_width_kernel(const unsigned char* __restrict__ m, int* __restrict__ widthOut)
{
    __shared__ int c1, c2, c4, c8, cp;
    if (threadIdx.x == 0) { c1 = c2 = c4 = c8 = cp = 0; }
    __syncthreads();
    int l1 = 0, l2 = 0, l4 = 0, l8 = 0, lp = 0;
    const unsigned short* m16 = (const unsigned short*)m;
    const unsigned int*   m32 = (const unsigned int*)m;
    for (int i = threadIdx.x; i < 16384; i += 256) l1 += (m[i] != 0);
    for (int i = threadIdx.x; i < 8192;  i += 256) {
        l2 += (m16[i] != 0);
        lp += ((m[2 * i] != 0) == (m[2 * i + 1] != 0));
    }
    for (int i = threadIdx.x; i < 4096;  i += 256) l4 += (m32[i] != 0);
    for (int i = threadIdx.x; i < 2048;  i += 256) l8 += ((m32[2 * i] | m32[2 * i + 1]) != 0);
    atomicAdd(&c1, l1); atomicAdd(&c2, l2); atomicAdd(&c4, l4);
    atomicAdd(&c8, l8); atomicAdd(&cp, lp);
    __syncthreads();
    if (threadIdx.x == 0) {
        const float f1 = fabsf(c1 / 16384.f - 0.5f);
        const float f2 = fabsf(c2 / 8192.f  - 0.5f);
        const float f4 = fabsf(c4 / 4096.f  - 0.5f);
        const float f8 = fabsf(c8 / 2048.f  - 0.5f);
        int w = 1; float best = f1;
        if (f2 < best) { best = f2; w = 2; }
        if (f4 < best) { best = f4; w = 4; }
        if (f8 < best) { best = f8; w = 8; }
        if (w == 1 && cp > 7400) w = 2;
        *widthOut = w;
    }
}

// ---------------------------------------------------------------------------
// Masked row softmax, bf16 in/out IN PLACE. One block per (b,t) row; each
// thread owns 16 elements (no cross-thread aliasing on the in-place write).
// ---------------------------------------------------------------------------
__global__ __launch_bounds__(256)
void softmax_kernel(__hip_bfloat16* __restrict__ S, const void* __restrict__ mask,
                    const int* __restrict__ widthPtr, int L, int T)
{
    const int row  = blockIdx.x;          // b*T + t
    const int bidx = row / T;
    __hip_bfloat16* Srow = S + (long)row * L;

    const int w = *widthPtr;
    const unsigned char*  m8  = (const unsigned char*)mask;
    const unsigned short* m16 = (const unsigned short*)mask;
    const unsigned int*   m32 = (const unsigned int*)mask;
    const uint2*          m64 = (const uint2*)mask;

    const int tid = threadIdx.x;
    float v[16];
    float mx = -INFINITY;
    #pragma unroll
    for (int i = 0; i < 16; ++i) {
        const int l = tid + i * 256;
        const long idx = (long)bidx * L + l;
        bool masked;
        if (w == 4)      masked = (m32[idx] != 0);
        else if (w == 1) masked = (m8[idx] != 0);
        else if (w == 2) masked = (m16[idx] != 0);
        else             { uint2 q = m64[idx]; masked = ((q.x | q.y) != 0); }
        float x = __bfloat162float(Srow[l]);
        if (masked) x = -INFINITY;
        v[i] = x;
        mx = fmaxf(mx, x);
    }
    #pragma unroll
    for (int off = 1; off < 64; off <<= 1)
        mx = fmaxf(mx, __shfl_xor(mx, off, 64));
    __shared__ float redmx[4];
    if ((tid & 63) == 0) redmx[tid >> 6] = mx;
    __syncthreads();
    mx = fmaxf(fmaxf(redmx[0], redmx[1]), fmaxf(redmx[2], redmx[3]));

    float s = 0.f;
    #pragma unroll
    for (int i = 0; i < 16; ++i) {
        const float e = (v[i] == -INFINITY) ? 0.f : __expf(v[i] - mx);
        v[i] = e;
        s += e;
    }
    #pragma unroll
    for (int off = 1; off < 64; off <<= 1)
        s += __shfl_xor(s, off, 64);
    __shared__ float redsm[4];
    if ((tid & 63) == 0) redsm[tid >> 6] = s;
    __syncthreads();
    s = redsm[0] + redsm[1] + redsm[2] + redsm[3];
    const float inv = (s > 0.f) ? (1.f / s) : 0.f;

    #pragma unroll
    for (int i = 0; i < 16; ++i) {
        const int l = tid + i * 256;
        Srow[l] = __float2bfloat16(v[i] * inv);
    }
}

// ---------------------------------------------------------------------------
extern "C" void kernel_launch(void* const* d_in, const int* in_sizes, int n_in,
                              void* d_out, int out_size, void* d_ws, size_t ws_size,
                              hipStream_t stream)
{
    constexpr int B = 4, L = 4096, DH = 1024, T = 1024, DG = 768, P = 256;

    const float* H  = (const float*)d_in[0];
    const float* G  = (const float*)d_in[1];
    const void*  mask = d_in[2];
    const float* Wk = (const float*)d_in[3];
    const float* Wq = (const float*)d_in[4];
    for (int i = 0; i < n_in; ++i) {
        switch (in_sizes[i]) {
            case B * L * DH: H    = (const float*)d_in[i]; break;
            case B * T * DG: G    = (const float*)d_in[i]; break;
            case B * L:      mask = d_in[i];               break;
            case P * DH:     Wk   = (const float*)d_in[i]; break;
            case P * DG:     Wq   = (const float*)d_in[i]; break;
        }
    }
    float* Z = (float*)d_out;

    char* ws = (char*)d_ws;
    __hip_bfloat16* Hbf  = (__hip_bfloat16*)ws;                      // [0, 32 MiB)
    __hip_bfloat16* Ht   = (__hip_bfloat16*)(ws + (32l << 20));      // [32, 64)
    __hip_bfloat16* Gbf  = (__hip_bfloat16*)(ws + (64l << 20));      // [64, 70)
    __hip_bfloat16* Qbf  = (__hip_bfloat16*)(ws + (70l << 20));      // [70, 72)
    __hip_bfloat16* Kbf  = (__hip_bfloat16*)(ws + (72l << 20));      // [72, 80)
    __hip_bfloat16* Wkbf = (__hip_bfloat16*)(ws + (80l << 20));      // 512 KiB
    __hip_bfloat16* Wqbf = (__hip_bfloat16*)(ws + (80l << 20) + (512l << 10)); // 384 KiB
    __hip_bfloat16* Sb   = (__hip_bfloat16*)(ws + (81l << 20));      // [81, 113)
    int* widthFlag       = (int*)(ws + (70l << 20));                 // dead Qbf after S-pass

    const dim3 blk(256);

    // Zero the fp32 output (Z-pass accumulates via atomicAdd).
    hipMemsetAsync(d_out, 0, (size_t)out_size * sizeof(float), stream);

    // 0) input prep
    h_prep_kernel<<<dim3(L / 32, DH / 32, B), blk, 0, stream>>>(H, Hbf, Ht, L, DH);
    cvt_f32_bf16_kernel<<<dim3((P * DH) / 1024), blk, 0, stream>>>(Wk, (unsigned short*)Wkbf, (P * DH) / 4);
    cvt_f32_bf16_kernel<<<dim3((P * DG) / 1024), blk, 0, stream>>>(Wq, (unsigned short*)Wqbf, (P * DG) / 4);
    cvt_f32_bf16_kernel<<<dim3((B * T * DG) / 1024), blk, 0, stream>>>(G, (unsigned short*)Gbf, (B * T * DG) / 4);

    // 1) Q = G @ Wq^T   [B*T, P]
    gemm_bt_kernel<__hip_bfloat16, 1, false><<<dim3((B * T) / 128, P / 128, 1), blk, 0, stream>>>(
        Gbf, Wqbf, Qbf, DG, DG, DG, P, 0, 0, 0, 1.0f);
    // 2) K = H @ Wk^T   [B*L, P]
    gemm_bt_kernel<__hip_bfloat16, 1, false><<<dim3((B * L) / 128, P / 128, 1), blk, 0, stream>>>(
        Hbf, Wkbf, Kbf, DH, DH, DH, P, 0, 0, 0, 1.0f);
    // 3) S = Q @ K^T * P^-0.5   [B, T, L] bf16
    gemm_bt_kernel<__hip_bfloat16, 1, false><<<dim3(T / 128, L / 128, B), blk, 0, stream>>>(
        Qbf, Kbf, Sb, P, P, P, L,
        (long)T * P, (long)L * P, (long)T * L, 0.0625f);
    // 4) mask width detection (Qbf dead now)
    mask_width_kernel<<<dim3(1), blk, 0, stream>>>((const unsigned char*)mask, widthFlag);
    // 5) masked softmax -> alpha bf16 in place
    softmax_kernel<<<dim3(B * T), blk, 0, stream>>>(Sb, mask, widthFlag, L, T);
    // 6) Z += alpha @ Ht^T   split-K x4, fp32 atomic out
    gemm_bt_kernel<float, 4, true><<<dim3(T / 128, DH / 128, B * 4), blk, 0, stream>>>(
        Sb, Ht, Z, L, L, L, DH,
        (long)T * L, (long)DH * L, (long)T * DH, 1.0f);
}

// Round 8
// 356.365 us; speedup vs baseline: 1.0330x; 1.0056x over previous
//
#include <hip/hip_runtime.h>
#include <hip/hip_bf16.h>

// Problem: B=4, L=4096, DH=1024, T=1024, DG=768, P=256
// Inputs fp32 + bool mask (width auto-detect); OUTPUT fp32.
// Pipeline:
//   memset Z
//   0) h_prep: H fp32 -> Hbf [B*L,DH] + Ht [B,DH,L] (one read of H)
//      cvt G, Wk, Wq fp32 -> bf16
//   1) Qbf = Gbf @ Wqbf^T        [B*T, P]   bf16
//   2) Kbf = Hbf @ Wkbf^T        [B*L, P]   bf16
//   3) Sb  = Qbf @ Kbf^T / 16    [B, T, L]  bf16
//   4) mask width probe (flag in dead Qbf region)
//   5) masked softmax rows of Sb -> alpha bf16 in place (stride L)
//   6) Z  += alpha @ Ht^T  split-K x4, fp32 atomicAdd  [B, T, DH]
// GEMM K-loop uses global_load_lds width=16 (m97 ladder step: 517->874 TF).

typedef __attribute__((ext_vector_type(8))) short short8;   // 8 bf16 = 4 VGPRs
typedef __attribute__((ext_vector_type(4))) float f32x4;

static __device__ __forceinline__ unsigned short bf16bits(float x) {
    __hip_bfloat16 b = __float2bfloat16(x);
    return *(unsigned short*)&b;
}

// Async global->LDS, 16 B per lane. HW semantics (m104/m108): LDS dest =
// wave-uniform base + lane*16; gptr is per-lane. LDS layout must match.
static __device__ __forceinline__ void gload_lds16(const __hip_bfloat16* g,
                                                   __hip_bfloat16* l)
{
    auto gp = (const __attribute__((address_space(1))) unsigned int*)(uintptr_t)g;
    auto lp = (__attribute__((address_space(3))) unsigned int*)(unsigned int)(uintptr_t)l;
    __builtin_amdgcn_global_load_lds(gp, lp, 16, 0, 0);
}

// ---------------------------------------------------------------------------
// Elementwise fp32 -> bf16, 4 per thread. n4 = n/4.
// ---------------------------------------------------------------------------
__global__ __launch_bounds__(256)
void cvt_f32_bf16_kernel(const float* __restrict__ in,
                         unsigned short* __restrict__ out, int n4)
{
    const int i = blockIdx.x * 256 + threadIdx.x;
    if (i >= n4) return;
    float4 v = ((const float4*)in)[i];
    ushort4 o;
    o.x = bf16bits(v.x); o.y = bf16bits(v.y);
    o.z = bf16bits(v.z); o.w = bf16bits(v.w);
    ((ushort4*)out)[i] = o;
}

// ---------------------------------------------------------------------------
// H prep: one pass reads H fp32, writes Hbf (row-major bf16) and Ht
// (per-batch transpose, bf16). 32x32 tiles.
// ---------------------------------------------------------------------------
__global__ __launch_bounds__(256)
void h_prep_kernel(const float* __restrict__ H,
                   __hip_bfloat16* __restrict__ Hbf,
                   __hip_bfloat16* __restrict__ Ht, int L, int D)
{
    const long b = blockIdx.z;
    const float* Hb = H + b * (long)L * D;
    __hip_bfloat16* Hbfb = Hbf + b * (long)L * D;
    __hip_bfloat16* Htb  = Ht  + b * (long)D * L;
    __shared__ float tile[32][33];
    const int l0 = blockIdx.x * 32, d0 = blockIdx.y * 32;
    const int tx = threadIdx.x & 31, ty = threadIdx.x >> 5;  // 32 x 8
    #pragma unroll
    for (int j = 0; j < 4; ++j) {
        const float v = Hb[(long)(l0 + ty + j * 8) * D + d0 + tx];
        tile[ty + j * 8][tx] = v;
        Hbfb[(long)(l0 + ty + j * 8) * D + d0 + tx] = __float2bfloat16(v);
    }
    __syncthreads();
    #pragma unroll
    for (int j = 0; j < 4; ++j)
        Htb[(long)(d0 + ty + j * 8) * L + l0 + tx] = __float2bfloat16(tile[tx][ty + j * 8]);
}

// ---------------------------------------------------------------------------
// GEMM: C[M,N] (+)= scale * A[M,K] @ Bm[N,K]^T  (bf16 row-major, K contig)
// 128x128 tile, 4 waves, wave 64x64 via 4x4 MFMA 16x16x32 bf16.
// Staging: global_load_lds width=16 into UNPADDED As/Bs[128][32]
// (wave-uniform base + lane*16 — layout matches exactly).
// SPLITK: blockIdx.z = batch*SPLITK + kchunk. ATOMIC: fp32 atomicAdd out.
// ---------------------------------------------------------------------------
template <typename OutT, int SPLITK, bool ATOMIC>
__global__ __launch_bounds__(256)
void gemm_bt_kernel(const __hip_bfloat16* __restrict__ A,
                    const __hip_bfloat16* __restrict__ Bm,
                    OutT* __restrict__ C,
                    int K, int lda, int ldb, int ldc,
                    long batchStrideA, long batchStrideB, long batchStrideC,
                    float scale)
{
    const int zb = blockIdx.z / SPLITK;
    const int kc = blockIdx.z % SPLITK;
    A  += (long)zb * batchStrideA;
    Bm += (long)zb * batchStrideB;
    C  += (long)zb * batchStrideC;
    const int Kloc  = K / SPLITK;
    const int kbase = kc * Kloc;

    const int tid  = threadIdx.x;
    const int lane = tid & 63;
    const int wave = tid >> 6;
    const int wm = (wave & 1) * 64;
    const int wn = (wave >> 1) * 64;
    const int rowBase = blockIdx.x * 128;
    const int colBase = blockIdx.y * 128;

    __shared__ __hip_bfloat16 As[128][32];   // UNPADDED: global_load_lds layout
    __shared__ __hip_bfloat16 Bs[128][32];

    f32x4 acc[4][4];
    #pragma unroll
    for (int i = 0; i < 4; ++i)
        #pragma unroll
        for (int j = 0; j < 4; ++j)
            acc[i][j] = (f32x4){0.f, 0.f, 0.f, 0.f};

    // Staging: wave w covers rows [w*32, w*32+32) as two 16-row x 1024B chunks.
    // Lane i within chunk: row = i>>2, col = (i&3)*8  (16 B each).
    const int srow = lane >> 2;
    const int scol = (lane & 3) * 8;
    __hip_bfloat16* aC0 = &As[wave * 32][0];
    __hip_bfloat16* aC1 = &As[wave * 32 + 16][0];
    __hip_bfloat16* bC0 = &Bs[wave * 32][0];
    __hip_bfloat16* bC1 = &Bs[wave * 32 + 16][0];
    const long ar0 = (long)(rowBase + wave * 32 + srow) * lda;
    const long ar1 = ar0 + 16l * lda;
    const long br0 = (long)(colBase + wave * 32 + srow) * ldb;
    const long br1 = br0 + 16l * ldb;

    const int mrow = lane & 15;         // fragment m/n index
    const int koff = (lane >> 4) * 8;   // fragment k offset

    for (int k0 = 0; k0 < Kloc; k0 += 32) {
        const int kk = kbase + k0 + scol;
        __syncthreads();                 // prev iteration's ds_reads complete
        gload_lds16(A  + ar0 + kk, aC0);
        gload_lds16(A  + ar1 + kk, aC1);
        gload_lds16(Bm + br0 + kk, bC0);
        gload_lds16(Bm + br1 + kk, bC1);
        __syncthreads();                 // compiler drains vmcnt before barrier

        short8 af[4], bf[4];
        #pragma unroll
        for (int mi = 0; mi < 4; ++mi)
            af[mi] = *(const short8*)(&As[wm + mi * 16 + mrow][koff]);
        #pragma unroll
        for (int ni = 0; ni < 4; ++ni)
            bf[ni] = *(const short8*)(&Bs[wn + ni * 16 + mrow][koff]);

        #pragma unroll
        for (int mi = 0; mi < 4; ++mi)
            #pragma unroll
            for (int ni = 0; ni < 4; ++ni)
                acc[mi][ni] = __builtin_amdgcn_mfma_f32_16x16x32_bf16(
                    af[mi], bf[ni], acc[mi][ni], 0, 0, 0);
    }

    // C/D layout (verified m89/m91): col = lane&15, row = (lane>>4)*4 + r
    const int crow0 = (lane >> 4) * 4;
    const int ccol  = lane & 15;
    #pragma unroll
    for (int mi = 0; mi < 4; ++mi) {
        #pragma unroll
        for (int ni = 0; ni < 4; ++ni) {
            #pragma unroll
            for (int r = 0; r < 4; ++r) {
                const int row = rowBase + wm + mi * 16 + crow0 + r;
                const int col = colBase + wn + ni * 16 + ccol;
                const float v = acc[mi][ni][r] * scale;
                if constexpr (ATOMIC) {
                    atomicAdd(&C[(long)row * ldc + col], v);
                } else if constexpr (sizeof(OutT) == 2) {
                    C[(long)row * ldc + col] = __float2bfloat16(v);
                } else {
                    C[(long)row * ldc + col] = v;
                }
            }
        }
    }
}

// ---------------------------------------------------------------------------
// Mask element-width detector (16384 bools, ~50% True). Nonzero fractions at
// widths 1/2/4/8 B in the first 16384 bytes; true width ~0.5. Byte-vs-u16
// tie broken by byte-pair equality.
// ---------------------------------------------------------------------------
__global__ __launch_bounds__(256)
void mask_width_kernel(const unsigned char* __restrict__ m, int* __restrict__ widthOut)
{
    __shared__ int c1, c2, c4, c8, cp;
    if (threadIdx.x == 0) { c1 = c2 = c4 = c8 = cp = 0; }
    __syncthreads();
    int l1 = 0, l2 = 0, l4 = 0, l8 = 0, lp = 0;
    const unsigned short* m16 = (const unsigned short*)m;
    const unsigned int*   m32 = (const unsigned int*)m;
    for (int i = threadIdx.x; i < 16384; i += 256) l1 += (m[i] != 0);
    for (int i = threadIdx.x; i < 8192;  i += 256) {
        l2 += (m16[i] != 0);
        lp += ((m[2 * i] != 0) == (m[2 * i + 1] != 0));
    }
    for (int i = threadIdx.x; i < 4096;  i += 256) l4 += (m32[i] != 0);
    for (int i = threadIdx.x; i < 2048;  i += 256) l8 += ((m32[2 * i] | m32[2 * i + 1]) != 0);
    atomicAdd(&c1, l1); atomicAdd(&c2, l2); atomicAdd(&c4, l4);
    atomicAdd(&c8, l8); atomicAdd(&cp, lp);
    __syncthreads();
    if (threadIdx.x == 0) {
        const float f1 = fabsf(c1 / 16384.f - 0.5f);
        const float f2 = fabsf(c2 / 8192.f  - 0.5f);
        const float f4 = fabsf(c4 / 4096.f  - 0.5f);
        const float f8 = fabsf(c8 / 2048.f  - 0.5f);
        int w = 1; float best = f1;
        if (f2 < best) { best = f2; w = 2; }
        if (f4 < best) { best = f4; w = 4; }
        if (f8 < best) { best = f8; w = 8; }
        if (w == 1 && cp > 7400) w = 2;
        *widthOut = w;
    }
}

// ---------------------------------------------------------------------------
// Masked row softmax, bf16 in/out IN PLACE. One block per (b,t) row; each
// thread owns 16 elements (no cross-thread aliasing on the in-place write).
// ---------------------------------------------------------------------------
__global__ __launch_bounds__(256)
void softmax_kernel(__hip_bfloat16* __restrict__ S, const void* __restrict__ mask,
                    const int* __restrict__ widthPtr, int L, int T)
{
    const int row  = blockIdx.x;          // b*T + t
    const int bidx = row / T;
    __hip_bfloat16* Srow = S + (long)row * L;

    const int w = *widthPtr;
    const unsigned char*  m8  = (const unsigned char*)mask;
    const unsigned short* m16 = (const unsigned short*)mask;
    const unsigned int*   m32 = (const unsigned int*)mask;
    const uint2*          m64 = (const uint2*)mask;

    const int tid = threadIdx.x;
    float v[16];
    float mx = -INFINITY;
    #pragma unroll
    for (int i = 0; i < 16; ++i) {
        const int l = tid + i * 256;
        const long idx = (long)bidx * L + l;
        bool masked;
        if (w == 4)      masked = (m32[idx] != 0);
        else if (w == 1) masked = (m8[idx] != 0);
        else if (w == 2) masked = (m16[idx] != 0);
        else             { uint2 q = m64[idx]; masked = ((q.x | q.y) != 0); }
        float x = __bfloat162float(Srow[l]);
        if (masked) x = -INFINITY;
        v[i] = x;
        mx = fmaxf(mx, x);
    }
    #pragma unroll
    for (int off = 1; off < 64; off <<= 1)
        mx = fmaxf(mx, __shfl_xor(mx, off, 64));
    __shared__ float redmx[4];
    if ((tid & 63) == 0) redmx[tid >> 6] = mx;
    __syncthreads();
    mx = fmaxf(fmaxf(redmx[0], redmx[1]), fmaxf(redmx[2], redmx[3]));

    float s = 0.f;
    #pragma unroll
    for (int i = 0; i < 16; ++i) {
        const float e = (v[i] == -INFINITY) ? 0.f : __expf(v[i] - mx);
        v[i] = e;
        s += e;
    }
    #pragma unroll
    for (int off = 1; off < 64; off <<= 1)
        s += __shfl_xor(s, off, 64);
    __shared__ float redsm[4];
    if ((tid & 63) == 0) redsm[tid >> 6] = s;
    __syncthreads();
    s = redsm[0] + redsm[1] + redsm[2] + redsm[3];
    const float inv = (s > 0.f) ? (1.f / s) : 0.f;

    #pragma unroll
    for (int i = 0; i < 16; ++i) {
        const int l = tid + i * 256;
        Srow[l] = __float2bfloat16(v[i] * inv);
    }
}

// ---------------------------------------------------------------------------
extern "C" void kernel_launch(void* const* d_in, const int* in_sizes, int n_in,
                              void* d_out, int out_size, void* d_ws, size_t ws_size,
                              hipStream_t stream)
{
    constexpr int B = 4, L = 4096, DH = 1024, T = 1024, DG = 768, P = 256;

    const float* H  = (const float*)d_in[0];
    const float* G  = (const float*)d_in[1];
    const void*  mask = d_in[2];
    const float* Wk = (const float*)d_in[3];
    const float* Wq = (const float*)d_in[4];
    for (int i = 0; i < n_in; ++i) {
        switch (in_sizes[i]) {
            case B * L * DH: H    = (const float*)d_in[i]; break;
            case B * T * DG: G    = (const float*)d_in[i]; break;
            case B * L:      mask = d_in[i];               break;
            case P * DH:     Wk   = (const float*)d_in[i]; break;
            case P * DG:     Wq   = (const float*)d_in[i]; break;
        }
    }
    float* Z = (float*)d_out;

    char* ws = (char*)d_ws;
    __hip_bfloat16* Hbf  = (__hip_bfloat16*)ws;                      // [0, 32 MiB)
    __hip_bfloat16* Ht   = (__hip_bfloat16*)(ws + (32l << 20));      // [32, 64)
    __hip_bfloat16* Gbf  = (__hip_bfloat16*)(ws + (64l << 20));      // [64, 70)
    __hip_bfloat16* Qbf  = (__hip_bfloat16*)(ws + (70l << 20));      // [70, 72)
    __hip_bfloat16* Kbf  = (__hip_bfloat16*)(ws + (72l << 20));      // [72, 80)
    __hip_bfloat16* Wkbf = (__hip_bfloat16*)(ws + (80l << 20));      // 512 KiB
    __hip_bfloat16* Wqbf = (__hip_bfloat16*)(ws + (80l << 20) + (512l << 10)); // 384 KiB
    __hip_bfloat16* Sb   = (__hip_bfloat16*)(ws + (81l << 20));      // [81, 113)
    int* widthFlag       = (int*)(ws + (70l << 20));                 // dead Qbf after S-pass

    const dim3 blk(256);

    // Zero the fp32 output (Z-pass accumulates via atomicAdd).
    hipMemsetAsync(d_out, 0, (size_t)out_size * sizeof(float), stream);

    // 0) input prep
    h_prep_kernel<<<dim3(L / 32, DH / 32, B), blk, 0, stream>>>(H, Hbf, Ht, L, DH);
    cvt_f32_bf16_kernel<<<dim3((P * DH) / 1024), blk, 0, stream>>>(Wk, (unsigned short*)Wkbf, (P * DH) / 4);
    cvt_f32_bf16_kernel<<<dim3((P * DG) / 1024), blk, 0, stream>>>(Wq, (unsigned short*)Wqbf, (P * DG) / 4);
    cvt_f32_bf16_kernel<<<dim3((B * T * DG) / 1024), blk, 0, stream>>>(G, (unsigned short*)Gbf, (B * T * DG) / 4);

    // 1) Q = G @ Wq^T   [B*T, P]
    gemm_bt_kernel<__hip_bfloat16, 1, false><<<dim3((B * T) / 128, P / 128, 1), blk, 0, stream>>>(
        Gbf, Wqbf, Qbf, DG, DG, DG, P, 0, 0, 0, 1.0f);
    // 2) K = H @ Wk^T   [B*L, P]
    gemm_bt_kernel<__hip_bfloat16, 1, false><<<dim3((B * L) / 128, P / 128, 1), blk, 0, stream>>>(
        Hbf, Wkbf, Kbf, DH, DH, DH, P, 0, 0, 0, 1.0f);
    // 3) S = Q @ K^T * P^-0.5   [B, T, L] bf16
    gemm_bt_kernel<__hip_bfloat16, 1, false><<<dim3(T / 128, L / 128, B), blk, 0, stream>>>(
        Qbf, Kbf, Sb, P, P, P, L,
        (long)T * P, (long)L * P, (long)T * L, 0.0625f);
    // 4) mask width detection (Qbf dead now)
    mask_width_kernel<<<dim3(1), blk, 0, stream>>>((const unsigned char*)mask, widthFlag);
    // 5) masked softmax -> alpha bf16 in place
    softmax_kernel<<<dim3(B * T), blk, 0, stream>>>(Sb, mask, widthFlag, L, T);
    // 6) Z += alpha @ Ht^T   split-K x4, fp32 atomic out
    gemm_bt_kernel<float, 4, true><<<dim3(T / 128, DH / 128, B * 4), blk, 0, stream>>>(
        Sb, Ht, Z, L, L, L, DH,
        (long)T * L, (long)DH * L, (long)T * DH, 1.0f);
}

// Round 9
// 340.635 us; speedup vs baseline: 1.0807x; 1.0462x over previous
//
#include <hip/hip_runtime.h>
#include <hip/hip_bf16.h>

// Problem: B=4, L=4096, DH=1024, T=1024, DG=768, P=256
// Inputs fp32 + bool mask (width auto-detect); OUTPUT fp32.
// Pipeline:
//   memset Z
//   0) h_prep: H fp32 -> Hbf [B*L,DH] + Ht [B,DH,L]; cvt G,Wk,Wq -> bf16
//   1) Qbf = Gbf @ Wqbf^T        [B*T, P]   bf16
//   2) Kbf = Hbf @ Wkbf^T        [B*L, P]   bf16
//   3) Sb  = Qbf @ Kbf^T / 16    [B, T, L]  bf16
//   4) mask width probe
//   5) masked softmax rows of Sb -> alpha bf16 in place
//   6) Z  += alpha @ Ht^T  split-K x4, fp32 atomicAdd
// GEMM K-loop: DOUBLE-BUFFERED global_load_lds prefetch (one barrier/iter;
// load->drain distance = one full iteration of ds_read+MFMA).

typedef __attribute__((ext_vector_type(8))) short short8;   // 8 bf16 = 4 VGPRs
typedef __attribute__((ext_vector_type(4))) float f32x4;

static __device__ __forceinline__ unsigned short bf16bits(float x) {
    __hip_bfloat16 b = __float2bfloat16(x);
    return *(unsigned short*)&b;
}

// Async global->LDS, 16 B per lane. LDS dest = wave-uniform base + lane*16.
static __device__ __forceinline__ void gload_lds16(const __hip_bfloat16* g,
                                                   __hip_bfloat16* l)
{
    auto gp = (const __attribute__((address_space(1))) unsigned int*)(uintptr_t)g;
    auto lp = (__attribute__((address_space(3))) unsigned int*)(unsigned int)(uintptr_t)l;
    __builtin_amdgcn_global_load_lds(gp, lp, 16, 0, 0);
}

// ---------------------------------------------------------------------------
__global__ __launch_bounds__(256)
void cvt_f32_bf16_kernel(const float* __restrict__ in,
                         unsigned short* __restrict__ out, int n4)
{
    const int i = blockIdx.x * 256 + threadIdx.x;
    if (i >= n4) return;
    float4 v = ((const float4*)in)[i];
    ushort4 o;
    o.x = bf16bits(v.x); o.y = bf16bits(v.y);
    o.z = bf16bits(v.z); o.w = bf16bits(v.w);
    ((ushort4*)out)[i] = o;
}

// ---------------------------------------------------------------------------
// H prep: one read of H fp32 -> Hbf (row-major bf16) + Ht (transpose bf16).
// ---------------------------------------------------------------------------
__global__ __launch_bounds__(256)
void h_prep_kernel(const float* __restrict__ H,
                   __hip_bfloat16* __restrict__ Hbf,
                   __hip_bfloat16* __restrict__ Ht, int L, int D)
{
    const long b = blockIdx.z;
    const float* Hb = H + b * (long)L * D;
    __hip_bfloat16* Hbfb = Hbf + b * (long)L * D;
    __hip_bfloat16* Htb  = Ht  + b * (long)D * L;
    __shared__ float tile[32][33];
    const int l0 = blockIdx.x * 32, d0 = blockIdx.y * 32;
    const int tx = threadIdx.x & 31, ty = threadIdx.x >> 5;  // 32 x 8
    #pragma unroll
    for (int j = 0; j < 4; ++j) {
        const float v = Hb[(long)(l0 + ty + j * 8) * D + d0 + tx];
        tile[ty + j * 8][tx] = v;
        Hbfb[(long)(l0 + ty + j * 8) * D + d0 + tx] = __float2bfloat16(v);
    }
    __syncthreads();
    #pragma unroll
    for (int j = 0; j < 4; ++j)
        Htb[(long)(d0 + ty + j * 8) * L + l0 + tx] = __float2bfloat16(tile[tx][ty + j * 8]);
}

// ---------------------------------------------------------------------------
// GEMM: C[M,N] (+)= scale * A[M,K] @ Bm[N,K]^T  (bf16 row-major, K contig)
// 128x128 tile, 4 waves, wave 64x64 via 4x4 MFMA 16x16x32 bf16.
// DOUBLE-BUFFERED staging via global_load_lds width=16 into As/Bs[2][128][32].
// One barrier per k-iter; prefetch of tile k+1 issued right after it, so the
// vmcnt(0) drain at the NEXT barrier has a full iteration of compute between
// issue and wait (latency hidden).
// ---------------------------------------------------------------------------
template <typename OutT, int SPLITK, bool ATOMIC>
__global__ __launch_bounds__(256)
void gemm_bt_kernel(const __hip_bfloat16* __restrict__ A,
                    const __hip_bfloat16* __restrict__ Bm,
                    OutT* __restrict__ C,
                    int K, int lda, int ldb, int ldc,
                    long batchStrideA, long batchStrideB, long batchStrideC,
                    float scale)
{
    const int zb = blockIdx.z / SPLITK;
    const int kc = blockIdx.z % SPLITK;
    A  += (long)zb * batchStrideA;
    Bm += (long)zb * batchStrideB;
    C  += (long)zb * batchStrideC;
    const int Kloc  = K / SPLITK;
    const int kbase = kc * Kloc;

    const int tid  = threadIdx.x;
    const int lane = tid & 63;
    const int wave = tid >> 6;
    const int wm = (wave & 1) * 64;
    const int wn = (wave >> 1) * 64;
    const int rowBase = blockIdx.x * 128;
    const int colBase = blockIdx.y * 128;

    __shared__ __hip_bfloat16 As[2][128][32];   // unpadded: global_load_lds layout
    __shared__ __hip_bfloat16 Bs[2][128][32];

    f32x4 acc[4][4];
    #pragma unroll
    for (int i = 0; i < 4; ++i)
        #pragma unroll
        for (int j = 0; j < 4; ++j)
            acc[i][j] = (f32x4){0.f, 0.f, 0.f, 0.f};

    // Staging: wave w covers rows [w*32, w*32+32) as two 16-row x 1024 B chunks.
    // Lane i within a chunk: row = i>>2, col = (i&3)*8 (16 B each) — matches
    // the HW's (base + lane*16) scatter exactly.
    const int srow = lane >> 2;
    const int scol = (lane & 3) * 8;
    const long ar0 = (long)(rowBase + wave * 32 + srow) * lda;
    const long ar1 = ar0 + 16l * lda;
    const long br0 = (long)(colBase + wave * 32 + srow) * ldb;
    const long br1 = br0 + 16l * ldb;

    const int mrow = lane & 15;         // fragment m/n index
    const int koff = (lane >> 4) * 8;   // fragment k offset

    // Prologue: tile 0 -> buffer 0
    {
        const int kk = kbase + scol;
        gload_lds16(A  + ar0 + kk, &As[0][wave * 32][0]);
        gload_lds16(A  + ar1 + kk, &As[0][wave * 32 + 16][0]);
        gload_lds16(Bm + br0 + kk, &Bs[0][wave * 32][0]);
        gload_lds16(Bm + br1 + kk, &Bs[0][wave * 32 + 16][0]);
    }

    int cur = 0;
    for (int k0 = 0; k0 < Kloc; k0 += 32) {
        __syncthreads();   // drains vmcnt: buf[cur] ready; prev ds_reads done
        if (k0 + 32 < Kloc) {
            const int kk = kbase + k0 + 32 + scol;
            const int nxt = cur ^ 1;
            gload_lds16(A  + ar0 + kk, &As[nxt][wave * 32][0]);
            gload_lds16(A  + ar1 + kk, &As[nxt][wave * 32 + 16][0]);
            gload_lds16(Bm + br0 + kk, &Bs[nxt][wave * 32][0]);
            gload_lds16(Bm + br1 + kk, &Bs[nxt][wave * 32 + 16][0]);
        }

        short8 af[4], bf[4];
        #pragma unroll
        for (int mi = 0; mi < 4; ++mi)
            af[mi] = *(const short8*)(&As[cur][wm + mi * 16 + mrow][koff]);
        #pragma unroll
        for (int ni = 0; ni < 4; ++ni)
            bf[ni] = *(const short8*)(&Bs[cur][wn + ni * 16 + mrow][koff]);

        #pragma unroll
        for (int mi = 0; mi < 4; ++mi)
            #pragma unroll
            for (int ni = 0; ni < 4; ++ni)
                acc[mi][ni] = __builtin_amdgcn_mfma_f32_16x16x32_bf16(
                    af[mi], bf[ni], acc[mi][ni], 0, 0, 0);
        cur ^= 1;
    }

    // C/D layout (verified m89/m91): col = lane&15, row = (lane>>4)*4 + r
    const int crow0 = (lane >> 4) * 4;
    const int ccol  = lane & 15;
    #pragma unroll
    for (int mi = 0; mi < 4; ++mi) {
        #pragma unroll
        for (int ni = 0; ni < 4; ++ni) {
            #pragma unroll
            for (int r = 0; r < 4; ++r) {
                const int row = rowBase + wm + mi * 16 + crow0 + r;
                const int col = colBase + wn + ni * 16 + ccol;
                const float v = acc[mi][ni][r] * scale;
                if constexpr (ATOMIC) {
                    atomicAdd(&C[(long)row * ldc + col], v);
                } else if constexpr (sizeof(OutT) == 2) {
                    C[(long)row * ldc + col] = __float2bfloat16(v);
                } else {
                    C[(long)row * ldc + col] = v;
                }
            }
        }
    }
}

// ---------------------------------------------------------------------------
// Mask element-width detector (16384 bools, ~50% True).
// ---------------------------------------------------------------------------
__global__ __launch_bounds__(256)
void mask_width_kernel(const unsigned char* __restrict__ m, int* __restrict__ widthOut)
{
    __shared__ int c1, c2, c4, c8, cp;
    if (threadIdx.x == 0) { c1 = c2 = c4 = c8 = cp = 0; }
    __syncthreads();
    int l1 = 0, l2 = 0, l4 = 0, l8 = 0, lp = 0;
    const unsigned short* m16 = (const unsigned short*)m;
    const unsigned int*   m32 = (const unsigned int*)m;
    for (int i = threadIdx.x; i < 16384; i += 256) l1 += (m[i] != 0);
    for (int i = threadIdx.x; i < 8192;  i += 256) {
        l2 += (m16[i] != 0);
        lp += ((m[2 * i] != 0) == (m[2 * i + 1] != 0));
    }
    for (int i = threadIdx.x; i < 4096;  i += 256) l4 += (m32[i] != 0);
    for (int i = threadIdx.x; i < 2048;  i += 256) l8 += ((m32[2 * i] | m32[2 * i + 1]) != 0);
    atomicAdd(&c1, l1); atomicAdd(&c2, l2); atomicAdd(&c4, l4);
    atomicAdd(&c8, l8); atomicAdd(&cp, lp);
    __syncthreads();
    if (threadIdx.x == 0) {
        const float f1 = fabsf(c1 / 16384.f - 0.5f);
        const float f2 = fabsf(c2 / 8192.f  - 0.5f);
        const float f4 = fabsf(c4 / 4096.f  - 0.5f);
        const float f8 = fabsf(c8 / 2048.f  - 0.5f);
        int w = 1; float best = f1;
        if (f2 < best) { best = f2; w = 2; }
        if (f4 < best) { best = f4; w = 4; }
        if (f8 < best) { best = f8; w = 8; }
        if (w == 1 && cp > 7400) w = 2;
        *widthOut = w;
    }
}

// ---------------------------------------------------------------------------
// Masked row softmax, bf16 in/out IN PLACE. One block per (b,t) row.
// ---------------------------------------------------------------------------
__global__ __launch_bounds__(256)
void softmax_kernel(__hip_bfloat16* __restrict__ S, const void* __restrict__ mask,
                    const int* __restrict__ widthPtr, int L, int T)
{
    const int row  = blockIdx.x;          // b*T + t
    const int bidx = row / T;
    __hip_bfloat16* Srow = S + (long)row * L;

    const int w = *widthPtr;
    const unsigned char*  m8  = (const unsigned char*)mask;
    const unsigned short* m16 = (const unsigned short*)mask;
    const unsigned int*   m32 = (const unsigned int*)mask;
    const uint2*          m64 = (const uint2*)mask;

    const int tid = threadIdx.x;
    float v[16];
    float mx = -INFINITY;
    #pragma unroll
    for (int i = 0; i < 16; ++i) {
        const int l = tid + i * 256;
        const long idx = (long)bidx * L + l;
        bool masked;
        if (w == 4)      masked = (m32[idx] != 0);
        else if (w == 1) masked = (m8[idx] != 0);
        else if (w == 2) masked = (m16[idx] != 0);
        else             { uint2 q = m64[idx]; masked = ((q.x | q.y) != 0); }
        float x = __bfloat162float(Srow[l]);
        if (masked) x = -INFINITY;
        v[i] = x;
        mx = fmaxf(mx, x);
    }
    #pragma unroll
    for (int off = 1; off < 64; off <<= 1)
        mx = fmaxf(mx, __shfl_xor(mx, off, 64));
    __shared__ float redmx[4];
    if ((tid & 63) == 0) redmx[tid >> 6] = mx;
    __syncthreads();
    mx = fmaxf(fmaxf(redmx[0], redmx[1]), fmaxf(redmx[2], redmx[3]));

    float s = 0.f;
    #pragma unroll
    for (int i = 0; i < 16; ++i) {
        const float e = (v[i] == -INFINITY) ? 0.f : __expf(v[i] - mx);
        v[i] = e;
        s += e;
    }
    #pragma unroll
    for (int off = 1; off < 64; off <<= 1)
        s += __shfl_xor(s, off, 64);
    __shared__ float redsm[4];
    if ((tid & 63) == 0) redsm[tid >> 6] = s;
    __syncthreads();
    s = redsm[0] + redsm[1] + redsm[2] + redsm[3];
    const float inv = (s > 0.f) ? (1.f / s) : 0.f;

    #pragma unroll
    for (int i = 0; i < 16; ++i) {
        const int l = tid + i * 256;
        Srow[l] = __float2bfloat16(v[i] * inv);
    }
}

// ---------------------------------------------------------------------------
extern "C" void kernel_launch(void* const* d_in, const int* in_sizes, int n_in,
                              void* d_out, int out_size, void* d_ws, size_t ws_size,
                              hipStream_t stream)
{
    constexpr int B = 4, L = 4096, DH = 1024, T = 1024, DG = 768, P = 256;

    const float* H  = (const float*)d_in[0];
    const float* G  = (const float*)d_in[1];
    const void*  mask = d_in[2];
    const float* Wk = (const float*)d_in[3];
    const float* Wq = (const float*)d_in[4];
    for (int i = 0; i < n_in; ++i) {
        switch (in_sizes[i]) {
            case B * L * DH: H    = (const float*)d_in[i]; break;
            case B * T * DG: G    = (const float*)d_in[i]; break;
            case B * L:      mask = d_in[i];               break;
            case P * DH:     Wk   = (const float*)d_in[i]; break;
            case P * DG:     Wq   = (const float*)d_in[i]; break;
        }
    }
    float* Z = (float*)d_out;

    char* ws = (char*)d_ws;
    __hip_bfloat16* Hbf  = (__hip_bfloat16*)ws;                      // [0, 32 MiB)
    __hip_bfloat16* Ht   = (__hip_bfloat16*)(ws + (32l << 20));      // [32, 64)
    __hip_bfloat16* Gbf  = (__hip_bfloat16*)(ws + (64l << 20));      // [64, 70)
    __hip_bfloat16* Qbf  = (__hip_bfloat16*)(ws + (70l << 20));      // [70, 72)
    __hip_bfloat16* Kbf  = (__hip_bfloat16*)(ws + (72l << 20));      // [72, 80)
    __hip_bfloat16* Wkbf = (__hip_bfloat16*)(ws + (80l << 20));      // 512 KiB
    __hip_bfloat16* Wqbf = (__hip_bfloat16*)(ws + (80l << 20) + (512l << 10)); // 384 KiB
    __hip_bfloat16* Sb   = (__hip_bfloat16*)(ws + (81l << 20));      // [81, 113)
    int* widthFlag       = (int*)(ws + (70l << 20));                 // dead Qbf after S-pass

    const dim3 blk(256);

    // Zero the fp32 output (Z-pass accumulates via atomicAdd).
    hipMemsetAsync(d_out, 0, (size_t)out_size * sizeof(float), stream);

    // 0) input prep
    h_prep_kernel<<<dim3(L / 32, DH / 32, B), blk, 0, stream>>>(H, Hbf, Ht, L, DH);
    cvt_f32_bf16_kernel<<<dim3((P * DH) / 1024), blk, 0, stream>>>(Wk, (unsigned short*)Wkbf, (P * DH) / 4);
    cvt_f32_bf16_kernel<<<dim3((P * DG) / 1024), blk, 0, stream>>>(Wq, (unsigned short*)Wqbf, (P * DG) / 4);
    cvt_f32_bf16_kernel<<<dim3((B * T * DG) / 1024), blk, 0, stream>>>(G, (unsigned short*)Gbf, (B * T * DG) / 4);

    // 1) Q = G @ Wq^T   [B*T, P]
    gemm_bt_kernel<__hip_bfloat16, 1, false><<<dim3((B * T) / 128, P / 128, 1), blk, 0, stream>>>(
        Gbf, Wqbf, Qbf, DG, DG, DG, P, 0, 0, 0, 1.0f);
    // 2) K = H @ Wk^T   [B*L, P]
    gemm_bt_kernel<__hip_bfloat16, 1, false><<<dim3((B * L) / 128, P / 128, 1), blk, 0, stream>>>(
        Hbf, Wkbf, Kbf, DH, DH, DH, P, 0, 0, 0, 1.0f);
    // 3) S = Q @ K^T * P^-0.5   [B, T, L] bf16
    gemm_bt_kernel<__hip_bfloat16, 1, false><<<dim3(T / 128, L / 128, B), blk, 0, stream>>>(
        Qbf, Kbf, Sb, P, P, P, L,
        (long)T * P, (long)L * P, (long)T * L, 0.0625f);
    // 4) mask width detection (Qbf dead now)
    mask_width_kernel<<<dim3(1), blk, 0, stream>>>((const unsigned char*)mask, widthFlag);
    // 5) masked softmax -> alpha bf16 in place
    softmax_kernel<<<dim3(B * T), blk, 0, stream>>>(Sb, mask, widthFlag, L, T);
    // 6) Z += alpha @ Ht^T   split-K x4, fp32 atomic out
    gemm_bt_kernel<float, 4, true><<<dim3(T / 128, DH / 128, B * 4), blk, 0, stream>>>(
        Sb, Ht, Z, L, L, L, DH,
        (long)T * L, (long)DH * L, (long)T * DH, 1.0f);
}